// Round 8
// baseline (25.666 us; speedup 1.0000x reference)
//
#include <hip/hip_runtime.h>
#include <math.h>

#define DIM 256
#define NLAYERS 64

typedef __attribute__((ext_vector_type(8))) short short8;
typedef __attribute__((ext_vector_type(4))) float f32x4;

// ---------- helpers ----------
__device__ __forceinline__ float dpp_shl1_zero(float v) {
    int r = __builtin_amdgcn_update_dpp(0, __float_as_int(v), 0x130, 0xF, 0xF, true);
    return __int_as_float(r);
}
__device__ __forceinline__ float dpp_shr1_keep(float oldv, float v) {
    int r = __builtin_amdgcn_update_dpp(__float_as_int(oldv), __float_as_int(v), 0x138, 0xF, 0xF, false);
    return __int_as_float(r);
}
// f32 -> bf16 bits, RNE (cold path: build_m only).
__device__ __forceinline__ unsigned short f2bf(float f) {
    unsigned u = __float_as_uint(f);
    u += 0x7FFFu + ((u >> 16) & 1u);
    return (unsigned short)(u >> 16);
}
// packed f32x2 -> bf16x2 (RNE), single VALU op (no builtin on gfx950, m240).
__device__ __forceinline__ unsigned cvtpk_bf16(float a, float b) {
    unsigned r;
    asm("v_cvt_pk_bf16_f32 %0, %1, %2" : "=v"(r) : "v"(a), "v"(b));
    return r;
}

// ---------- kernel 1: build M in MFMA-fragment order (bf16) ----------
// 16 blocks x 1024 threads: 16 waves (4/SIMD) each push one identity row
// through the 64 layers; 4 chains/SIMD hide the LDS table-read latency.
// Row k of M stored at fragment granule:
//   bfrag[(((col>>4)*8 + (k>>5))*64 + ((k>>3)&3)*16 + (col&15))*8 + (k&7)]
__global__ __launch_bounds__(1024)
void build_m_kernel(const float* __restrict__ theta, unsigned short* __restrict__ bfrag) {
    __shared__ float tbl[NLAYERS * DIM];   // 64 KB: [(l*128+p)*2 + {c,s}]
    const int tid = threadIdx.x;
    #pragma unroll
    for (int kk = 0; kk < 8; ++kk) {
        int idx = tid + 1024 * kk;         // idx = l*128 + p
        int l = idx >> 7, p = idx & 127;
        float a = 2.0f * theta[idx];
        float s = __sinf(a), c = __cosf(a);
        if ((l & 1) && (p == 127)) { c = 1.0f; s = 0.0f; }   // odd-layer passthrough pair
        tbl[idx * 2 + 0] = c;
        tbl[idx * 2 + 1] = s;
    }
    __syncthreads();

    const int w = tid >> 6;
    const int t = tid & 63;
    const int row = blockIdx.x * 16 + w;   // 0..255

    float e[4];
    #pragma unroll
    for (int j = 0; j < 4; ++j) e[j] = (4 * t + j == row) ? 1.0f : 0.0f;

    const float4* tbl4 = (const float4*)tbl;
    #pragma unroll 2
    for (int l = 0; l < NLAYERS; l += 2) {
        float4 cs = tbl4[(l << 6) + t];
        {
            float a0 = e[0], a1 = e[1], a2 = e[2], a3 = e[3];
            e[0] = cs.x * a0 + cs.y * a1;
            e[1] = cs.y * a0 - cs.x * a1;
            e[2] = cs.z * a2 + cs.w * a3;
            e[3] = cs.w * a2 - cs.z * a3;
        }
        float4 cs1 = tbl4[((l + 1) << 6) + t];
        {
            float a1 = e[1], a2 = e[2], a3 = e[3];
            float n1 = cs1.x * a1 + cs1.y * a2;
            float n2 = cs1.y * a1 - cs1.x * a2;
            float xjn = dpp_shl1_zero(e[0]);
            float n3  = cs1.z * a3 + cs1.w * xjn;
            float snd = cs1.w * a3 - cs1.z * xjn;
            e[0] = dpp_shr1_keep(e[0], snd);
            e[1] = n1; e[2] = n2; e[3] = n3;
        }
    }

    const int kt = row >> 5, g8 = (row >> 3) & 3, ki = row & 7;
    #pragma unroll
    for (int j = 0; j < 4; ++j) {
        int col = 4 * t + j;
        bfrag[(((col >> 4) * 8 + kt) * 64 + g8 * 16 + (col & 15)) * 8 + ki] = f2bf(e[j]);
    }
}

// ---------- kernel 2: out = x @ M — reg-staged bf16 LDS fragments ----------
// 512 blocks x 512 threads (8 waves); wave w owns output cols [32w,32w+32).
// 64 rows/block = 4 chunks of 16 rows. Staging (T14): thread (r=tid>>5,
// o=tid&31) loads 8 f32 of row r, k-octet o (coalesced), converts ONCE via
// v_cvt_pk_bf16, and ds_write_b128's the finished A-fragment granule:
//   byte = kt*1024 + g*256 + r*16  (kt=o>>2, g=o&3), XOR-swizzled ^((o&7)<<4)
// -> writer lanes 8/bank-group, reader (granule kt*1024+t*16 ^ ((kt*4+g)&7)<<4)
// 8/bank-group: both conflict-free. LDS chunk = 8KB bf16 (half of f32), and
// each wave reads only 8 ds_read_b128/chunk. All global traffic is reg loads
// -> compiler emits precise per-reg waitcnts (no vmcnt(0) drains; stores never
// waited). Manual sync = lgkmcnt(0)+s_barrier+sched_barrier per chunk only.
// k enumeration k = kt*32 + 8*(t>>4) + i identical for A and B (hw perm cancels).
// C/D: col=lane&15, row=(lane>>4)*4+reg [m89].
__global__ __launch_bounds__(512, 4)
void clements_gemm(const float* __restrict__ x,
                   const unsigned short* __restrict__ bfrag,
                   float* __restrict__ out) {
    __shared__ unsigned short abf[4][4096];   // 4 chunks x 8 KB bf16 fragments

    const int tid = threadIdx.x;
    const int w   = tid >> 6;       // wave 0..7
    const int t   = tid & 63;
    const int l16 = t & 15;
    const int g   = t >> 4;         // 0..3
    const long rowbase = (long)blockIdx.x * 64;

    // staging map: thread -> (row in chunk, k-octet)
    const int sr = tid >> 5;        // 0..15
    const int so = tid & 31;        // 0..31
    char* const wbase = (char*)&abf[0][0] +
        ((((so >> 2) * 1024) + ((so & 3) * 256) + (sr * 16)) ^ ((so & 7) << 4));
    const float* const xp = x + (rowbase + sr) * 256 + so * 8;

    f32x4 pa[4], pb[4];
#define LOADR(i) { pa[i] = *(const f32x4*)(xp + (i) * 16 * 256);       \
                   pb[i] = *(const f32x4*)(xp + (i) * 16 * 256 + 4); }
#define CVTW(i) { union { short8 s; unsigned u[4]; } h;                \
        h.u[0] = cvtpk_bf16(pa[i][0], pa[i][1]);                       \
        h.u[1] = cvtpk_bf16(pa[i][2], pa[i][3]);                       \
        h.u[2] = cvtpk_bf16(pb[i][0], pb[i][1]);                       \
        h.u[3] = cvtpk_bf16(pb[i][2], pb[i][3]);                       \
        *(short8*)(wbase + (i) * 8192) = h.s; }
#define BAR() { asm volatile("s_waitcnt lgkmcnt(0)" ::: "memory");     \
                __builtin_amdgcn_s_barrier();                          \
                __builtin_amdgcn_sched_barrier(0); }

    // --- B preload (coalesced 16B/lane from fragment-ordered bfrag, L2-hot)
    short8 Bf[8][2];
    {
        const short8* bp = (const short8*)bfrag;
        #pragma unroll
        for (int nt = 0; nt < 2; ++nt)
            #pragma unroll
            for (int kt = 0; kt < 8; ++kt)
                Bf[kt][nt] = bp[((w * 2 + nt) * 8 + kt) * 64 + t];
    }

    // --- prologue: 3 chunks of x loads in flight, stage chunk 0
    LOADR(0) LOADR(1) LOADR(2)
    CVTW(0)
    BAR()

    const char* const rbase = (const char*)&abf[0][0];
    auto compute = [&](int i) {
        f32x4 a0 = {0.f,0.f,0.f,0.f}, a1 = {0.f,0.f,0.f,0.f};
        #pragma unroll
        for (int kt = 0; kt < 8; ++kt) {
            short8 A = *(const short8*)(rbase + (i) * 8192 +
                ((kt * 1024 + t * 16) ^ (((kt * 4 + g) & 7) << 4)));
            a0 = __builtin_amdgcn_mfma_f32_16x16x32_bf16(A, Bf[kt][0], a0, 0, 0, 0);
            a1 = __builtin_amdgcn_mfma_f32_16x16x32_bf16(A, Bf[kt][1], a1, 0, 0, 0);
        }
        float* o = out + (rowbase + i * 16 + g * 4) * 256 + 32 * w + l16;
        #pragma unroll
        for (int j = 0; j < 4; ++j) {
            o[(long)j * 256 +  0] = a0[j];
            o[(long)j * 256 + 16] = a1[j];
        }
    };

    LOADR(3)
    compute(0);
    CVTW(1)
    BAR()
    compute(1);
    CVTW(2)
    BAR()
    compute(2);
    CVTW(3)
    BAR()
    compute(3);
#undef LOADR
#undef CVTW
#undef BAR
}

// ---------- fallback: verified R1 direct kernel (ws too small) ----------
__global__ __launch_bounds__(1024, 4)
void clements_direct(const float* __restrict__ x,
                     const float* __restrict__ theta,
                     float* __restrict__ out) {
    __shared__ float tbl[NLAYERS * DIM];
    const int tid = threadIdx.x;
    #pragma unroll
    for (int k = 0; k < 8; ++k) {
        int idx = tid + 1024 * k;
        int l = idx >> 7;
        int p = idx & 127;
        float s, c;
        sincosf(2.0f * theta[idx], &s, &c);
        if ((l & 1) && (p == 127)) { c = 1.0f; s = 0.0f; }
        tbl[idx * 2 + 0] = c;
        tbl[idx * 2 + 1] = s;
    }
    __syncthreads();
    const int w = tid >> 6;
    const int t = tid & 63;
    const long base = ((long)blockIdx.x * 16 + w) * 8;
    float e[8][4];
    #pragma unroll
    for (int r = 0; r < 8; ++r) {
        float4 v = ((const float4*)(x + (base + r) * (long)DIM))[t];
        e[r][0] = v.x; e[r][1] = v.y; e[r][2] = v.z; e[r][3] = v.w;
    }
    const float4* tbl4 = (const float4*)tbl;
    #pragma unroll 2
    for (int l = 0; l < NLAYERS; l += 2) {
        float4 cs = tbl4[(l << 6) + t];
        #pragma unroll
        for (int r = 0; r < 8; ++r) {
            float a0 = e[r][0], a1 = e[r][1], a2 = e[r][2], a3 = e[r][3];
            e[r][0] = cs.x * a0 + cs.y * a1;
            e[r][1] = cs.y * a0 - cs.x * a1;
            e[r][2] = cs.z * a2 + cs.w * a3;
            e[r][3] = cs.w * a2 - cs.z * a3;
        }
        float4 cs1 = tbl4[((l + 1) << 6) + t];
        #pragma unroll
        for (int r = 0; r < 8; ++r) {
            float a1 = e[r][1], a2 = e[r][2], a3 = e[r][3];
            float n1 = cs1.x * a1 + cs1.y * a2;
            float n2 = cs1.y * a1 - cs1.x * a2;
            float xjn = dpp_shl1_zero(e[r][0]);
            float n3  = cs1.z * a3 + cs1.w * xjn;
            float snd = cs1.w * a3 - cs1.z * xjn;
            e[r][0] = dpp_shr1_keep(e[r][0], snd);
            e[r][1] = n1; e[r][2] = n2; e[r][3] = n3;
        }
    }
    #pragma unroll
    for (int r = 0; r < 8; ++r) {
        float4 v;
        v.x = e[r][0]; v.y = e[r][1]; v.z = e[r][2]; v.w = e[r][3];
        ((float4*)(out + (base + r) * (long)DIM))[t] = v;
    }
}

extern "C" void kernel_launch(void* const* d_in, const int* in_sizes, int n_in,
                              void* d_out, int out_size, void* d_ws, size_t ws_size,
                              hipStream_t stream) {
    const float* x     = (const float*)d_in[0];
    const float* theta = (const float*)d_in[1];
    float* out = (float*)d_out;

    const size_t need = (size_t)DIM * DIM * sizeof(unsigned short);  // bfrag, 128 KB
    if (ws_size >= need) {
        unsigned short* bfrag = (unsigned short*)d_ws;
        hipLaunchKernelGGL(build_m_kernel, dim3(16),  dim3(1024), 0, stream, theta, bfrag);
        hipLaunchKernelGGL(clements_gemm,  dim3(512), dim3(512),  0, stream, x, bfrag, out);
    } else {
        hipLaunchKernelGGL(clements_direct, dim3(256), dim3(1024), 0, stream, x, theta, out);
    }
}

// Round 9
// 25.237 us; speedup vs baseline: 1.0170x; 1.0170x over previous
//
#include <hip/hip_runtime.h>
#include <math.h>

#define DIM 256
#define NLAYERS 64

typedef __attribute__((ext_vector_type(8))) short short8;
typedef __attribute__((ext_vector_type(4))) float f32x4;

// ---------- helpers ----------
__device__ __forceinline__ float dpp_shl1_zero(float v) {
    int r = __builtin_amdgcn_update_dpp(0, __float_as_int(v), 0x130, 0xF, 0xF, true);
    return __int_as_float(r);
}
__device__ __forceinline__ float dpp_shr1_keep(float oldv, float v) {
    int r = __builtin_amdgcn_update_dpp(__float_as_int(oldv), __float_as_int(v), 0x138, 0xF, 0xF, false);
    return __int_as_float(r);
}
// f32 -> bf16 bits, RNE (cold path: build_m only).
__device__ __forceinline__ unsigned short f2bf(float f) {
    unsigned u = __float_as_uint(f);
    u += 0x7FFFu + ((u >> 16) & 1u);
    return (unsigned short)(u >> 16);
}
// packed f32x2 -> bf16x2 (RNE), single VALU op (no builtin on gfx950, m240).
__device__ __forceinline__ unsigned cvtpk_bf16(float a, float b) {
    unsigned r;
    asm("v_cvt_pk_bf16_f32 %0, %1, %2" : "=v"(r) : "v"(a), "v"(b));
    return r;
}

// ---------- kernel 1: build M in MFMA-fragment order (bf16) ----------
// 16 blocks x 1024 threads: 16 waves (4/SIMD) each push one identity row
// through the 64 layers. Row k of M stored at fragment granule:
//   bfrag[(((col>>4)*8 + (k>>5))*64 + ((k>>3)&3)*16 + (col&15))*8 + (k&7)]
__global__ __launch_bounds__(1024)
void build_m_kernel(const float* __restrict__ theta, unsigned short* __restrict__ bfrag) {
    __shared__ float tbl[NLAYERS * DIM];   // 64 KB: [(l*128+p)*2 + {c,s}]
    const int tid = threadIdx.x;
    #pragma unroll
    for (int kk = 0; kk < 8; ++kk) {
        int idx = tid + 1024 * kk;         // idx = l*128 + p
        int l = idx >> 7, p = idx & 127;
        float a = 2.0f * theta[idx];
        float s = __sinf(a), c = __cosf(a);
        if ((l & 1) && (p == 127)) { c = 1.0f; s = 0.0f; }   // odd-layer passthrough pair
        tbl[idx * 2 + 0] = c;
        tbl[idx * 2 + 1] = s;
    }
    __syncthreads();

    const int w = tid >> 6;
    const int t = tid & 63;
    const int row = blockIdx.x * 16 + w;   // 0..255

    float e[4];
    #pragma unroll
    for (int j = 0; j < 4; ++j) e[j] = (4 * t + j == row) ? 1.0f : 0.0f;

    const float4* tbl4 = (const float4*)tbl;
    #pragma unroll 2
    for (int l = 0; l < NLAYERS; l += 2) {
        float4 cs = tbl4[(l << 6) + t];
        {
            float a0 = e[0], a1 = e[1], a2 = e[2], a3 = e[3];
            e[0] = cs.x * a0 + cs.y * a1;
            e[1] = cs.y * a0 - cs.x * a1;
            e[2] = cs.z * a2 + cs.w * a3;
            e[3] = cs.w * a2 - cs.z * a3;
        }
        float4 cs1 = tbl4[((l + 1) << 6) + t];
        {
            float a1 = e[1], a2 = e[2], a3 = e[3];
            float n1 = cs1.x * a1 + cs1.y * a2;
            float n2 = cs1.y * a1 - cs1.x * a2;
            float xjn = dpp_shl1_zero(e[0]);
            float n3  = cs1.z * a3 + cs1.w * xjn;
            float snd = cs1.w * a3 - cs1.z * xjn;
            e[0] = dpp_shr1_keep(e[0], snd);
            e[1] = n1; e[2] = n2; e[3] = n3;
        }
    }

    const int kt = row >> 5, g8 = (row >> 3) & 3, ki = row & 7;
    #pragma unroll
    for (int j = 0; j < 4; ++j) {
        int col = 4 * t + j;
        bfrag[(((col >> 4) * 8 + kt) * 64 + g8 * 16 + (col & 15)) * 8 + ki] = f2bf(e[j]);
    }
}

// ---------- kernel 2: out = x @ M — reg-staged bf16 fragments, depth-2 ------
// 256 blocks x 512 threads (8 waves); wave w owns output cols [32w,32w+32).
// 128 rows/block = 8 chunks of 16 rows (B preload amortized 2x vs R8; B:A
// traffic 1:1). Staging (T14): thread (sr=tid>>5, so=tid&31) loads 8 f32 of
// row sr / k-octet so (coalesced 32B/lane), converts ONCE (v_cvt_pk), and
// ds_write_b128's the finished fragment granule at
//   byte = (kt*1024 + g*256 + sr*16) ^ ((so&7)<<4)   [layout verified R8]
// LDS = 2 x 8 KB ping-pong. Prefetch regs pa/pb[2] (16 VGPR) -> total ~115,
// no spill at the (512,4) 128-reg cap. All global loads are reg loads
// (compiler-precise waitcnts, no vmcnt drains); manual sync per chunk =
// lgkmcnt(0) + s_barrier + sched_barrier(0) only.
// k enumeration k = kt*32 + 8*(t>>4) + i identical for A and B (hw perm cancels).
// C/D: col=lane&15, row=(lane>>4)*4+reg [m89].
__global__ __launch_bounds__(512, 4)
void clements_gemm(const float* __restrict__ x,
                   const unsigned short* __restrict__ bfrag,
                   float* __restrict__ out) {
    __shared__ unsigned short abf[2][4096];   // ping-pong, 2 x 8 KB

    const int tid = threadIdx.x;
    const int w   = tid >> 6;       // wave 0..7
    const int t   = tid & 63;
    const int l16 = t & 15;
    const int g   = t >> 4;         // 0..3
    const long rowbase = (long)blockIdx.x * 128;

    // staging map: thread -> (row in chunk, k-octet)
    const int sr = tid >> 5;        // 0..15
    const int so = tid & 31;        // 0..31
    const int wsw = (((so >> 2) * 1024) + ((so & 3) * 256) + (sr * 16)) ^ ((so & 7) << 4);
    const float* const xp = x + (rowbase + sr) * 256 + so * 8;

    f32x4 pa[2], pb[2];
#define LOADR(i) { pa[(i) & 1] = *(const f32x4*)(xp + (i) * 16 * 256);       \
                   pb[(i) & 1] = *(const f32x4*)(xp + (i) * 16 * 256 + 4); }
#define CVTW(i) { union { short8 s; unsigned u[4]; } h;                      \
        h.u[0] = cvtpk_bf16(pa[(i) & 1][0], pa[(i) & 1][1]);                 \
        h.u[1] = cvtpk_bf16(pa[(i) & 1][2], pa[(i) & 1][3]);                 \
        h.u[2] = cvtpk_bf16(pb[(i) & 1][0], pb[(i) & 1][1]);                 \
        h.u[3] = cvtpk_bf16(pb[(i) & 1][2], pb[(i) & 1][3]);                 \
        *(short8*)((char*)&abf[(i) & 1][0] + wsw) = h.s; }
#define BAR() { asm volatile("s_waitcnt lgkmcnt(0)" ::: "memory");           \
                __builtin_amdgcn_s_barrier();                                \
                __builtin_amdgcn_sched_barrier(0); }

    // --- B preload (coalesced 16B/lane from fragment-ordered bfrag, L2-hot)
    short8 Bf[8][2];
    {
        const short8* bp = (const short8*)bfrag;
        #pragma unroll
        for (int nt = 0; nt < 2; ++nt)
            #pragma unroll
            for (int kt = 0; kt < 8; ++kt)
                Bf[kt][nt] = bp[((w * 2 + nt) * 8 + kt) * 64 + t];
    }

    auto compute = [&](int i) {
        f32x4 a0 = {0.f,0.f,0.f,0.f}, a1 = {0.f,0.f,0.f,0.f};
        const char* rb = (const char*)&abf[i & 1][0];
        #pragma unroll
        for (int kt = 0; kt < 8; ++kt) {
            short8 A = *(const short8*)(rb +
                ((kt * 1024 + t * 16) ^ (((kt * 4 + g) & 7) << 4)));
            a0 = __builtin_amdgcn_mfma_f32_16x16x32_bf16(A, Bf[kt][0], a0, 0, 0, 0);
            a1 = __builtin_amdgcn_mfma_f32_16x16x32_bf16(A, Bf[kt][1], a1, 0, 0, 0);
        }
        float* o = out + (rowbase + i * 16 + g * 4) * 256 + 32 * w + l16;
        #pragma unroll
        for (int j = 0; j < 4; ++j) {
            o[(long)j * 256 +  0] = a0[j];
            o[(long)j * 256 + 16] = a1[j];
        }
    };

    // --- prologue: 2 chunks of loads in flight, stage chunk 0
    LOADR(0) LOADR(1)
    CVTW(0)
    BAR()

    // --- main pipeline: LOAD(c+2) | compute(c) | CVTW(c+1) | BAR
    #pragma unroll
    for (int c = 0; c < 8; ++c) {
        if (c + 2 < 8) LOADR(c + 2)
        compute(c);
        if (c + 1 < 8) {
            CVTW(c + 1)
            BAR()
        }
    }
#undef LOADR
#undef CVTW
#undef BAR
}

// ---------- fallback: verified R1 direct kernel (ws too small) ----------
__global__ __launch_bounds__(1024, 4)
void clements_direct(const float* __restrict__ x,
                     const float* __restrict__ theta,
                     float* __restrict__ out) {
    __shared__ float tbl[NLAYERS * DIM];
    const int tid = threadIdx.x;
    #pragma unroll
    for (int k = 0; k < 8; ++k) {
        int idx = tid + 1024 * k;
        int l = idx >> 7;
        int p = idx & 127;
        float s, c;
        sincosf(2.0f * theta[idx], &s, &c);
        if ((l & 1) && (p == 127)) { c = 1.0f; s = 0.0f; }
        tbl[idx * 2 + 0] = c;
        tbl[idx * 2 + 1] = s;
    }
    __syncthreads();
    const int w = tid >> 6;
    const int t = tid & 63;
    const long base = ((long)blockIdx.x * 16 + w) * 8;
    float e[8][4];
    #pragma unroll
    for (int r = 0; r < 8; ++r) {
        float4 v = ((const float4*)(x + (base + r) * (long)DIM))[t];
        e[r][0] = v.x; e[r][1] = v.y; e[r][2] = v.z; e[r][3] = v.w;
    }
    const float4* tbl4 = (const float4*)tbl;
    #pragma unroll 2
    for (int l = 0; l < NLAYERS; l += 2) {
        float4 cs = tbl4[(l << 6) + t];
        #pragma unroll
        for (int r = 0; r < 8; ++r) {
            float a0 = e[r][0], a1 = e[r][1], a2 = e[r][2], a3 = e[r][3];
            e[r][0] = cs.x * a0 + cs.y * a1;
            e[r][1] = cs.y * a0 - cs.x * a1;
            e[r][2] = cs.z * a2 + cs.w * a3;
            e[r][3] = cs.w * a2 - cs.z * a3;
        }
        float4 cs1 = tbl4[((l + 1) << 6) + t];
        #pragma unroll
        for (int r = 0; r < 8; ++r) {
            float a1 = e[r][1], a2 = e[r][2], a3 = e[r][3];
            float n1 = cs1.x * a1 + cs1.y * a2;
            float n2 = cs1.y * a1 - cs1.x * a2;
            float xjn = dpp_shl1_zero(e[r][0]);
            float n3  = cs1.z * a3 + cs1.w * xjn;
            float snd = cs1.w * a3 - cs1.z * xjn;
            e[r][0] = dpp_shr1_keep(e[r][0], snd);
            e[r][1] = n1; e[r][2] = n2; e[r][3] = n3;
        }
    }
    #pragma unroll
    for (int r = 0; r < 8; ++r) {
        float4 v;
        v.x = e[r][0]; v.y = e[r][1]; v.z = e[r][2]; v.w = e[r][3];
        ((float4*)(out + (base + r) * (long)DIM))[t] = v;
    }
}

extern "C" void kernel_launch(void* const* d_in, const int* in_sizes, int n_in,
                              void* d_out, int out_size, void* d_ws, size_t ws_size,
                              hipStream_t stream) {
    const float* x     = (const float*)d_in[0];
    const float* theta = (const float*)d_in[1];
    float* out = (float*)d_out;

    const size_t need = (size_t)DIM * DIM * sizeof(unsigned short);  // bfrag, 128 KB
    if (ws_size >= need) {
        unsigned short* bfrag = (unsigned short*)d_ws;
        hipLaunchKernelGGL(build_m_kernel, dim3(16),  dim3(1024), 0, stream, theta, bfrag);
        hipLaunchKernelGGL(clements_gemm,  dim3(256), dim3(512),  0, stream, x, bfrag, out);
    } else {
        hipLaunchKernelGGL(clements_direct, dim3(256), dim3(1024), 0, stream, x, theta, out);
    }
}

// Round 10
// 24.040 us; speedup vs baseline: 1.0676x; 1.0498x over previous
//
#include <hip/hip_runtime.h>
#include <math.h>

#define DIM 256
#define NLAYERS 64

typedef __attribute__((ext_vector_type(8))) short short8;
typedef __attribute__((ext_vector_type(4))) float f32x4;

// ---------- helpers ----------
__device__ __forceinline__ float dpp_shl1_zero(float v) {
    int r = __builtin_amdgcn_update_dpp(0, __float_as_int(v), 0x130, 0xF, 0xF, true);
    return __int_as_float(r);
}
__device__ __forceinline__ float dpp_shr1_keep(float oldv, float v) {
    int r = __builtin_amdgcn_update_dpp(__float_as_int(oldv), __float_as_int(v), 0x138, 0xF, 0xF, false);
    return __int_as_float(r);
}
// f32 -> bf16 bits, RNE (cold path: build_m only).
__device__ __forceinline__ unsigned short f2bf(float f) {
    unsigned u = __float_as_uint(f);
    u += 0x7FFFu + ((u >> 16) & 1u);
    return (unsigned short)(u >> 16);
}
// packed f32x2 -> bf16x2 (RNE), single VALU op (no builtin on gfx950, m240).
__device__ __forceinline__ unsigned cvtpk_bf16(float a, float b) {
    unsigned r;
    asm("v_cvt_pk_bf16_f32 %0, %1, %2" : "=v"(r) : "v"(a), "v"(b));
    return r;
}

// ---------- kernel 1: build M in MFMA-fragment order (bf16) ----------
// 64 blocks x 256 threads (4 waves x 1 identity row): only 256 ds_read_b128
// per CU (~1.3us) vs 16-wave config's ~5us. Fast trig via __sinf/__cosf
// (~1e-6 err << bf16 quantization). Row k of M stored at fragment granule:
//   bfrag[(((col>>4)*8 + (k>>5))*64 + ((k>>3)&3)*16 + (col&15))*8 + (k&7)]
__global__ __launch_bounds__(256)
void build_m_kernel(const float* __restrict__ theta, unsigned short* __restrict__ bfrag) {
    __shared__ float tbl[NLAYERS * DIM];   // 64 KB: [(l*128+p)*2 + {c,s}]
    const int tid = threadIdx.x;
    #pragma unroll 4
    for (int kk = 0; kk < 32; ++kk) {
        int idx = tid + 256 * kk;          // idx = l*128 + p
        int l = idx >> 7, p = idx & 127;
        float a = 2.0f * theta[idx];
        float s = __sinf(a), c = __cosf(a);
        if ((l & 1) && (p == 127)) { c = 1.0f; s = 0.0f; }   // odd-layer passthrough pair
        tbl[idx * 2 + 0] = c;
        tbl[idx * 2 + 1] = s;
    }
    __syncthreads();

    const int w = tid >> 6;
    const int t = tid & 63;
    const int row = blockIdx.x * 4 + w;    // 0..255

    float e[4];
    #pragma unroll
    for (int j = 0; j < 4; ++j) e[j] = (4 * t + j == row) ? 1.0f : 0.0f;

    const float4* tbl4 = (const float4*)tbl;
    #pragma unroll 2
    for (int l = 0; l < NLAYERS; l += 2) {
        float4 cs = tbl4[(l << 6) + t];
        {
            float a0 = e[0], a1 = e[1], a2 = e[2], a3 = e[3];
            e[0] = cs.x * a0 + cs.y * a1;
            e[1] = cs.y * a0 - cs.x * a1;
            e[2] = cs.z * a2 + cs.w * a3;
            e[3] = cs.w * a2 - cs.z * a3;
        }
        float4 cs1 = tbl4[((l + 1) << 6) + t];
        {
            float a1 = e[1], a2 = e[2], a3 = e[3];
            float n1 = cs1.x * a1 + cs1.y * a2;
            float n2 = cs1.y * a1 - cs1.x * a2;
            float xjn = dpp_shl1_zero(e[0]);
            float n3  = cs1.z * a3 + cs1.w * xjn;
            float snd = cs1.w * a3 - cs1.z * xjn;
            e[0] = dpp_shr1_keep(e[0], snd);
            e[1] = n1; e[2] = n2; e[3] = n3;
        }
    }

    const int kt = row >> 5, g8 = (row >> 3) & 3, ki = row & 7;
    #pragma unroll
    for (int j = 0; j < 4; ++j) {
        int col = 4 * t + j;
        bfrag[(((col >> 4) * 8 + kt) * 64 + g8 * 16 + (col & 15)) * 8 + ki] = f2bf(e[j]);
    }
}

// ---------- kernel 2: out = x @ M — reg-staged bf16 fragments, depth-2 ------
// 512 blocks x 512 threads (8 waves); wave w owns output cols [32w,32w+32).
// 64 rows/block = 4 chunks of 16 rows. VGPR ~113 < 128 -> 2 blocks/CU
// (16 waves/CU): cross-block waves fill barrier stalls, and bytes-in-flight
// = 2 blocks x 16KB = 32KB/CU > ~22KB BDP -> BW-saturating.
// Staging (T14): thread (sr=tid>>5, so=tid&31) loads 8 f32 of row sr,
// k-octet so (coalesced 32B/lane), converts ONCE (v_cvt_pk), ds_write_b128's
// the finished fragment granule at byte = (kt*1024+g*256+sr*16) ^ ((so&7)<<4)
// [layout+swizzle verified R8/R9: writer & reader both 8 lanes/bank-group].
// LDS = 2 x 8 KB ping-pong. All global loads are reg loads (compiler-precise
// waitcnts, no vmcnt drains); per-chunk sync = lgkmcnt(0)+s_barrier+sched_barrier.
// k enumeration k = kt*32 + 8*(t>>4) + i identical for A and B (hw perm cancels).
// C/D: col=lane&15, row=(lane>>4)*4+reg [m89].
__global__ __launch_bounds__(512, 4)
void clements_gemm(const float* __restrict__ x,
                   const unsigned short* __restrict__ bfrag,
                   float* __restrict__ out) {
    __shared__ unsigned short abf[2][4096];   // ping-pong, 2 x 8 KB

    const int tid = threadIdx.x;
    const int w   = tid >> 6;       // wave 0..7
    const int t   = tid & 63;
    const int l16 = t & 15;
    const int g   = t >> 4;         // 0..3
    const long rowbase = (long)blockIdx.x * 64;

    // staging map: thread -> (row in chunk, k-octet)
    const int sr = tid >> 5;        // 0..15
    const int so = tid & 31;        // 0..31
    const int wsw = (((so >> 2) * 1024) + ((so & 3) * 256) + (sr * 16)) ^ ((so & 7) << 4);
    const float* const xp = x + (rowbase + sr) * 256 + so * 8;

    f32x4 pa[2], pb[2];
#define LOADR(i) { pa[(i) & 1] = *(const f32x4*)(xp + (i) * 16 * 256);       \
                   pb[(i) & 1] = *(const f32x4*)(xp + (i) * 16 * 256 + 4); }
#define CVTW(i) { union { short8 s; unsigned u[4]; } h;                      \
        h.u[0] = cvtpk_bf16(pa[(i) & 1][0], pa[(i) & 1][1]);                 \
        h.u[1] = cvtpk_bf16(pa[(i) & 1][2], pa[(i) & 1][3]);                 \
        h.u[2] = cvtpk_bf16(pb[(i) & 1][0], pb[(i) & 1][1]);                 \
        h.u[3] = cvtpk_bf16(pb[(i) & 1][2], pb[(i) & 1][3]);                 \
        *(short8*)((char*)&abf[(i) & 1][0] + wsw) = h.s; }
#define BAR() { asm volatile("s_waitcnt lgkmcnt(0)" ::: "memory");           \
                __builtin_amdgcn_s_barrier();                                \
                __builtin_amdgcn_sched_barrier(0); }

    // --- B preload (coalesced 16B/lane from fragment-ordered bfrag, L2-hot)
    short8 Bf[8][2];
    {
        const short8* bp = (const short8*)bfrag;
        #pragma unroll
        for (int nt = 0; nt < 2; ++nt)
            #pragma unroll
            for (int kt = 0; kt < 8; ++kt)
                Bf[kt][nt] = bp[((w * 2 + nt) * 8 + kt) * 64 + t];
    }

    auto compute = [&](int i) {
        f32x4 a0 = {0.f,0.f,0.f,0.f}, a1 = {0.f,0.f,0.f,0.f};
        const char* rb = (const char*)&abf[i & 1][0];
        #pragma unroll
        for (int kt = 0; kt < 8; ++kt) {
            short8 A = *(const short8*)(rb +
                ((kt * 1024 + t * 16) ^ (((kt * 4 + g) & 7) << 4)));
            a0 = __builtin_amdgcn_mfma_f32_16x16x32_bf16(A, Bf[kt][0], a0, 0, 0, 0);
            a1 = __builtin_amdgcn_mfma_f32_16x16x32_bf16(A, Bf[kt][1], a1, 0, 0, 0);
        }
        float* o = out + (rowbase + i * 16 + g * 4) * 256 + 32 * w + l16;
        #pragma unroll
        for (int j = 0; j < 4; ++j) {
            o[(long)j * 256 +  0] = a0[j];
            o[(long)j * 256 + 16] = a1[j];
        }
    };

    // --- prologue: 2 chunks of loads in flight, stage chunk 0
    LOADR(0) LOADR(1)
    CVTW(0)
    BAR()

    // --- main pipeline: LOAD(c+2) | compute(c) | CVTW(c+1) | BAR
    #pragma unroll
    for (int c = 0; c < 4; ++c) {
        if (c + 2 < 4) LOADR(c + 2)
        compute(c);
        if (c + 1 < 4) {
            CVTW(c + 1)
            BAR()
        }
    }
#undef LOADR
#undef CVTW
#undef BAR
}

// ---------- fallback: verified R1 direct kernel (ws too small) ----------
__global__ __launch_bounds__(1024, 4)
void clements_direct(const float* __restrict__ x,
                     const float* __restrict__ theta,
                     float* __restrict__ out) {
    __shared__ float tbl[NLAYERS * DIM];
    const int tid = threadIdx.x;
    #pragma unroll
    for (int k = 0; k < 8; ++k) {
        int idx = tid + 1024 * k;
        int l = idx >> 7;
        int p = idx & 127;
        float s, c;
        sincosf(2.0f * theta[idx], &s, &c);
        if ((l & 1) && (p == 127)) { c = 1.0f; s = 0.0f; }
        tbl[idx * 2 + 0] = c;
        tbl[idx * 2 + 1] = s;
    }
    __syncthreads();
    const int w = tid >> 6;
    const int t = tid & 63;
    const long base = ((long)blockIdx.x * 16 + w) * 8;
    float e[8][4];
    #pragma unroll
    for (int r = 0; r < 8; ++r) {
        float4 v = ((const float4*)(x + (base + r) * (long)DIM))[t];
        e[r][0] = v.x; e[r][1] = v.y; e[r][2] = v.z; e[r][3] = v.w;
    }
    const float4* tbl4 = (const float4*)tbl;
    #pragma unroll 2
    for (int l = 0; l < NLAYERS; l += 2) {
        float4 cs = tbl4[(l << 6) + t];
        #pragma unroll
        for (int r = 0; r < 8; ++r) {
            float a0 = e[r][0], a1 = e[r][1], a2 = e[r][2], a3 = e[r][3];
            e[r][0] = cs.x * a0 + cs.y * a1;
            e[r][1] = cs.y * a0 - cs.x * a1;
            e[r][2] = cs.z * a2 + cs.w * a3;
            e[r][3] = cs.w * a2 - cs.z * a3;
        }
        float4 cs1 = tbl4[((l + 1) << 6) + t];
        #pragma unroll
        for (int r = 0; r < 8; ++r) {
            float a1 = e[r][1], a2 = e[r][2], a3 = e[r][3];
            float n1 = cs1.x * a1 + cs1.y * a2;
            float n2 = cs1.y * a1 - cs1.x * a2;
            float xjn = dpp_shl1_zero(e[r][0]);
            float n3  = cs1.z * a3 + cs1.w * xjn;
            float snd = cs1.w * a3 - cs1.z * xjn;
            e[r][0] = dpp_shr1_keep(e[r][0], snd);
            e[r][1] = n1; e[r][2] = n2; e[r][3] = n3;
        }
    }
    #pragma unroll
    for (int r = 0; r < 8; ++r) {
        float4 v;
        v.x = e[r][0]; v.y = e[r][1]; v.z = e[r][2]; v.w = e[r][3];
        ((float4*)(out + (base + r) * (long)DIM))[t] = v;
    }
}

extern "C" void kernel_launch(void* const* d_in, const int* in_sizes, int n_in,
                              void* d_out, int out_size, void* d_ws, size_t ws_size,
                              hipStream_t stream) {
    const float* x     = (const float*)d_in[0];
    const float* theta = (const float*)d_in[1];
    float* out = (float*)d_out;

    const size_t need = (size_t)DIM * DIM * sizeof(unsigned short);  // bfrag, 128 KB
    if (ws_size >= need) {
        unsigned short* bfrag = (unsigned short*)d_ws;
        hipLaunchKernelGGL(build_m_kernel, dim3(64),  dim3(256), 0, stream, theta, bfrag);
        hipLaunchKernelGGL(clements_gemm,  dim3(512), dim3(512), 0, stream, x, bfrag, out);
    } else {
        hipLaunchKernelGGL(clements_direct, dim3(256), dim3(1024), 0, stream, x, theta, out);
    }
}